// Round 19
// baseline (82.042 us; speedup 1.0000x reference)
//
#include <hip/hip_runtime.h>
#include <math.h>

// GptOssRouter: T=16384, H=2880, E=128, K=4.
// r19 = r12 skeleton with the ONE remaining unvaried knob: per-CU global-load
// bytes. TM=64, grid=256 (1 block/CU), NT=512; 8 waves = 8 expert-16-groups,
// wave tile 64tok x 16exp -> w read ONCE per block, no inter-wave duplication:
// w traffic 737 -> 368 MB, per-CU bytes 3.6 -> 2.16 MB.
// K0: pre-split w (fp32 -> bf16 h/l, trunc-exact) into d_ws as 16x16x32
//     B-frag tiles (r12 layout). K1: x split h/l into swizzled LDS (3 bufs,
//     depth-3 reg prefetch); 3-pass split-bf16 MFMA xh*wh+xh*wl+xl*wh
//     (err ~1e-5); fused stripe-top8 + certified-gap (TAU=2.5e-4) -> fast
//     fp32 softmax; rare fp64 rescore (order == float64 numpy reference).

#define T_TOK 16384
#define HDIM  2880
#define EEXP  128
#define KTOP  4

#define TM   64
#define NT   512
#define KC   64
#define NCH  (HDIM / KC)     // 45 = 15 * 3
#define XBUF 16384           // 64 rows * 256 B
#define TAU  2.5e-4f

typedef __attribute__((ext_vector_type(8))) short bf16x8;
typedef __attribute__((ext_vector_type(4))) float f32x4;

#define MFMA(a, b, c) __builtin_amdgcn_mfma_f32_16x16x32_bf16((a), (b), (c), 0, 0, 0)

// ---------------- K0: w pre-split into fragment-tiled bf16 h/l -------------
__global__ __launch_bounds__(256) void w_split(
    const float* __restrict__ w, char* __restrict__ wp)
{
    const int gid  = blockIdx.x * 256 + threadIdx.x;   // 46080 total
    const int lane = gid & 63;
    const int q    = gid >> 6;        // 0..719
    const int ks   = q & 1;
    const int q2   = q >> 1;          // 0..359
    const int c    = q2 % NCH;
    const int F    = q2 / NCH;        // 0..7
    const int e    = F * 16 + (lane & 15);
    const int k0   = c * 64 + ks * 32 + (lane >> 4) * 8;

    const float* src = w + (size_t)e * HDIM + k0;
    float4 v0 = *(const float4*)(src);
    float4 v1 = *(const float4*)(src + 4);
    float vv[8] = {v0.x, v0.y, v0.z, v0.w, v1.x, v1.y, v1.z, v1.w};
    union { unsigned short s[8]; uint4 u; } H, L;
#pragma unroll
    for (int j = 0; j < 8; ++j) {
        unsigned u = __float_as_uint(vv[j]);
        H.s[j] = (unsigned short)(u >> 16);
        float rr = vv[j] - __uint_as_float(u & 0xffff0000u);
        L.s[j] = (unsigned short)(__float_as_uint(rr) >> 16);
    }
    const int tile = ((F * NCH + c) * 2 + ks) * 2;     // p=0 (h); l at +1
    *(uint4*)(wp + (size_t)tile * 1024 + lane * 16)       = H.u;
    *(uint4*)(wp + (size_t)(tile + 1) * 1024 + lane * 16) = L.u;
}

// x split: v = h + l (h = trunc_bf16(v), l = trunc_bf16(v - h), both exact);
// h 8B at swizzled slot, l at +128 within the 256B row.
static __device__ __forceinline__ void split_write256(char* base, int off, float4 v) {
    union { float4 v4; unsigned u[4]; } uv; uv.v4 = v;
    unsigned h01 = __builtin_amdgcn_perm(uv.u[1], uv.u[0], 0x07060302u);
    unsigned h23 = __builtin_amdgcn_perm(uv.u[3], uv.u[2], 0x07060302u);
    float r0 = v.x - __uint_as_float(uv.u[0] & 0xffff0000u);
    float r1 = v.y - __uint_as_float(uv.u[1] & 0xffff0000u);
    float r2 = v.z - __uint_as_float(uv.u[2] & 0xffff0000u);
    float r3 = v.w - __uint_as_float(uv.u[3] & 0xffff0000u);
    unsigned l01 = __builtin_amdgcn_perm(__float_as_uint(r1), __float_as_uint(r0), 0x07060302u);
    unsigned l23 = __builtin_amdgcn_perm(__float_as_uint(r3), __float_as_uint(r2), 0x07060302u);
    uint2 hw; hw.x = h01; hw.y = h23;
    uint2 lw; lw.x = l01; lw.y = l23;
    *(uint2*)(base + off)       = hw;
    *(uint2*)(base + off + 128) = lw;
}

// ---------------- K1: fused GEMM + selection --------------------------------
__global__ __launch_bounds__(NT, 2) void router_fused(
    const float* __restrict__ x, const char* __restrict__ wp,
    const float* __restrict__ w, const float* __restrict__ bias,
    float* __restrict__ out)
{
    __shared__ char smem[3 * XBUF];     // 49152 B
    const int tid  = threadIdx.x;
    const int tok0 = blockIdx.x * TM;
    const int lane = tid & 63;
    const int wv   = tid >> 6;          // expert 16-group 0..7
    const int r    = lane & 15;
    const int g    = lane >> 4;

    char* xb0 = smem;
    char* xb1 = smem + XBUF;
    char* xb2 = smem + 2 * XBUF;

    // x staging map: 1024 float4 / 512 thr = 2 per thread
    int xoff[2];
    const float* xptr[2];
#pragma unroll
    for (int i = 0; i < 2; ++i) {
        int f = tid + i * NT;
        int row = f >> 4, c4 = f & 15;
        xoff[i] = row * 256 + ((((c4 >> 1) ^ (row & 7)) << 4) | ((c4 & 1) << 3));
        xptr[i] = x + (size_t)(tok0 + row) * HDIM + c4 * 4;
    }

    // a-frag read offsets: [tokfrag 0..3][ks] (row&7 == r&7 since 16%8==0)
    int aoff[4][2];
#pragma unroll
    for (int tf = 0; tf < 4; ++tf) {
        int row = tf * 16 + r;
#pragma unroll
        for (int ks = 0; ks < 2; ++ks)
            aoff[tf][ks] = row * 256 + (((ks * 4 + g) ^ (row & 7)) << 4);
    }

    f32x4 acc[4];
    const f32x4 zf = {0.f, 0.f, 0.f, 0.f};
#pragma unroll
    for (int tf = 0; tf < 4; ++tf) acc[tf] = zf;

#define LOADX(pf, cc) do {                                            \
        pf[0] = *(const float4*)(xptr[0] + (cc) * KC);                \
        pf[1] = *(const float4*)(xptr[1] + (cc) * KC); } while (0)

#define WRITEX(pf, bb) do {                                           \
        split_write256((bb), xoff[0], pf[0]);                         \
        split_write256((bb), xoff[1], pf[1]); } while (0)

    // w frag tiles for wave's 16-expert group: W[ks*2 + p]
#define LOADW(W, cc) do {                                             \
        _Pragma("unroll")                                             \
        for (int ks_ = 0; ks_ < 2; ++ks_)                             \
        _Pragma("unroll")                                             \
        for (int p_ = 0; p_ < 2; ++p_)                                \
            W[ks_*2 + p_] = *(const bf16x8*)(wp +                     \
                (size_t)(((wv * NCH + (cc)) * 2 + ks_) * 2 + p_) * 1024 \
                + lane * 16); } while (0)

#define MFMA_CHUNK(cb, W) do {                                        \
        _Pragma("unroll")                                             \
        for (int ks_ = 0; ks_ < 2; ++ks_) {                           \
            bf16x8 bh = W[ks_*2], bl = W[ks_*2 + 1];                  \
            _Pragma("unroll")                                         \
            for (int tf_ = 0; tf_ < 4; ++tf_) {                       \
                bf16x8 ah = *(const bf16x8*)((cb) + aoff[tf_][ks_]);  \
                bf16x8 al = *(const bf16x8*)((cb) + aoff[tf_][ks_] + 128); \
                acc[tf_] = MFMA(ah, bh, acc[tf_]);                    \
                acc[tf_] = MFMA(ah, bl, acc[tf_]);                    \
                acc[tf_] = MFMA(al, bh, acc[tf_]);                    \
            }                                                         \
        } } while (0)

    float4 pfA[2], pfB[2], pfC[2];
    bf16x8 wA[4], wB[4], wC[4];

    // prologue: chunks 0..2 in regs, chunk 0 -> xb0; w chunks 0,1 in regs
    LOADX(pfA, 0); LOADX(pfB, 1); LOADX(pfC, 2);
    LOADW(wA, 0); LOADW(wB, 1);
    WRITEX(pfA, xb0);
    __syncthreads();

    for (int c = 0; c < NCH; c += 3) {
        // ---- phase 0: chunk c on xb0 / wA --------------------------------
        if (c + 3 < NCH) LOADX(pfA, c + 3);
        LOADW(wC, c + 2);
        MFMA_CHUNK(xb0, wA);
        WRITEX(pfB, xb1);                 // chunk c+1 (loaded 3 phases ago)
        __syncthreads();
        // ---- phase 1: chunk c+1 on xb1 / wB ------------------------------
        if (c + 3 < NCH) LOADW(wA, c + 3);
        if (c + 4 < NCH) LOADX(pfB, c + 4);
        MFMA_CHUNK(xb1, wB);
        WRITEX(pfC, xb2);                 // chunk c+2
        __syncthreads();
        // ---- phase 2: chunk c+2 on xb2 / wC ------------------------------
        if (c + 4 < NCH) LOADW(wB, c + 4);
        if (c + 5 < NCH) LOADX(pfC, c + 5);
        MFMA_CHUNK(xb2, wC);
        if (c + 3 < NCH) WRITEX(pfA, xb0); // chunk c+3
        __syncthreads();
    }

    // -------- logits(+bias) -> LDS [64][130] --------------------------------
    float* logitsL = (float*)smem;
    {
        const int e  = wv * 16 + r;
        const float bv = bias[e];
#pragma unroll
        for (int tf = 0; tf < 4; ++tf)
#pragma unroll
            for (int q = 0; q < 4; ++q) {
                int tok = tf * 16 + g * 4 + q;
                logitsL[tok * 130 + e] = acc[tf][q] + bv;
            }
    }
    float*  cvf = (float*) (smem + 33280);   // [64][8]
    int*    cie = (int*)   (smem + 35328);   // [64][8]
    int*    flg = (int*)   (smem + 37376);   // [64]
    double* svd = (double*)(smem + 37632);   // [64][4]
    int*    sid = (int*)   (smem + 39680);   // [64][4]
    double* cvd = (double*)(smem + 40704);   // [8]
    __syncthreads();

    // -------- stripe top-8: thread (t, s) scans experts [s*16, s*16+16) -----
    {
        const int t = tid >> 3, s = tid & 7;
        float v[8]; int id[8];
#pragma unroll
        for (int k = 0; k < 8; ++k) { v[k] = -3.4e38f; id[k] = 0x7fffffff; }
        for (int jj = 0; jj < 16; ++jj) {
            float lv = logitsL[t * 130 + s * 16 + jj];
            int   e  = s * 16 + jj;
            bool gt[8];
#pragma unroll
            for (int k = 0; k < 8; ++k)
                gt[k] = (lv > v[k]) || (lv == v[k] && e < id[k]);
#pragma unroll
            for (int k = 7; k >= 1; --k)
                if (gt[k - 1]) { v[k] = v[k - 1]; id[k] = id[k - 1]; }
#pragma unroll
            for (int k = 0; k < 8; ++k) {
                bool put = gt[k] && (k == 0 || !gt[k - 1]);
                if (put) { v[k] = lv; id[k] = e; }
            }
        }
#pragma unroll
        for (int rd = 0; rd < 8; ++rd) {
            float hv = v[0]; int hi = id[0];
#pragma unroll
            for (int off = 1; off < 8; off <<= 1) {
                float ov = __shfl_xor(hv, off);
                int   oi = __shfl_xor(hi, off);
                if (ov > hv || (ov == hv && oi < hi)) { hv = ov; hi = oi; }
            }
            if (s == 0) { cvf[t * 8 + rd] = hv; cie[t * 8 + rd] = hi; }
            bool mine = (v[0] == hv) && (id[0] == hi);
            if (mine) {
#pragma unroll
                for (int k = 0; k < 7; ++k) { v[k] = v[k + 1]; id[k] = id[k + 1]; }
                v[7] = -3.4e38f; id[7] = 0x7fffffff;
            }
        }
    }
    __syncthreads();

    // -------- certified-gap test + fast-path fill ---------------------------
    if (tid < TM) {
        float gmin = 3.4e38f;
#pragma unroll
        for (int k = 0; k < 4; ++k)
            gmin = fminf(gmin, cvf[tid * 8 + k] - cvf[tid * 8 + k + 1]);
        flg[tid] = (gmin < TAU);
    }
    if (tid < 256) {
        int t2 = tid >> 2, k = tid & 3;
        svd[t2 * 4 + k] = (double)cvf[t2 * 8 + k];
        sid[t2 * 4 + k] = cie[t2 * 8 + k];
    }
    __syncthreads();

    // -------- rare slow path: fp64 rescore (1 candidate per wave) -----------
    for (int ts = 0; ts < TM; ++ts) {
        if (!flg[ts]) continue;              // uniform across block
        {
            const int ce = cie[ts * 8 + wv];
            const float4* xr = (const float4*)(x + (size_t)(tok0 + ts) * HDIM);
            const float4* wr = (const float4*)(w + (size_t)ce * HDIM);
            double q0 = 0.0, q1 = 0.0, q2 = 0.0, q3 = 0.0;
            for (int i2 = 0; i2 < 12; ++i2) {
                int fi = lane + i2 * 64;
                if (fi < HDIM / 4) {
                    float4 xv = xr[fi];
                    float4 wv4 = wr[fi];
                    q0 = fma((double)xv.x, (double)wv4.x, q0);
                    q1 = fma((double)xv.y, (double)wv4.y, q1);
                    q2 = fma((double)xv.z, (double)wv4.z, q2);
                    q3 = fma((double)xv.w, (double)wv4.w, q3);
                }
            }
            double accd = (q0 + q2) + (q1 + q3);
#pragma unroll
            for (int off = 32; off > 0; off >>= 1)
                accd += __shfl_xor(accd, off);
            if (lane == 0) cvd[wv] = accd + (double)bias[ce];
        }
        __syncthreads();
        if (tid < 8) {                        // fp64 rank among 8 candidates
            double mv = cvd[tid]; int mi2 = cie[ts * 8 + tid];
            int rk = 0;
#pragma unroll
            for (int j2 = 0; j2 < 8; ++j2) {
                double oj = cvd[j2];
                rk += (oj > mv) || (oj == mv && cie[ts * 8 + j2] < mi2);
            }
            if (rk < 4) { svd[ts * 4 + rk] = mv; sid[ts * 4 + rk] = mi2; }
        }
        __syncthreads();
    }

    // -------- softmax + outputs ---------------------------------------------
    float* srow = (float*)smem;              // [64][128], overlays dead logits
    float4 z4 = make_float4(0.f, 0.f, 0.f, 0.f);
#pragma unroll
    for (int i = 0; i < 4; ++i)
        ((float4*)srow)[tid + i * NT] = z4;
    __syncthreads();

    if (tid < TM) {
        double m  = svd[tid * 4];
        double e0 = exp(svd[tid * 4 + 0] - m), e1 = exp(svd[tid * 4 + 1] - m);
        double e2 = exp(svd[tid * 4 + 2] - m), e3 = exp(svd[tid * 4 + 3] - m);
        double inv = 1.0 / ((e0 + e1) + (e2 + e3));
        float* oidx = out + (size_t)T_TOK * EEXP + (size_t)(tok0 + tid) * KTOP;
        int i0 = sid[tid * 4 + 0], i1 = sid[tid * 4 + 1];
        int i2 = sid[tid * 4 + 2], i3 = sid[tid * 4 + 3];
        oidx[0] = (float)i0; oidx[1] = (float)i1;
        oidx[2] = (float)i2; oidx[3] = (float)i3;
        srow[tid * EEXP + i0] = (float)(e0 * inv);
        srow[tid * EEXP + i1] = (float)(e1 * inv);
        srow[tid * EEXP + i2] = (float)(e2 * inv);
        srow[tid * EEXP + i3] = (float)(e3 * inv);
    }
    __syncthreads();

    float4* orow = (float4*)(out + (size_t)tok0 * EEXP);
#pragma unroll
    for (int i = 0; i < 4; ++i)
        orow[tid + i * NT] = ((float4*)srow)[tid + i * NT];
}

extern "C" void kernel_launch(void* const* d_in, const int* in_sizes, int n_in,
                              void* d_out, int out_size, void* d_ws, size_t ws_size,
                              hipStream_t stream) {
    const float* x    = (const float*)d_in[0];
    const float* w    = (const float*)d_in[1];
    const float* bias = (const float*)d_in[2];
    float* out        = (float*)d_out;
    char*  wp         = (char*)d_ws;   // 1440 KiB (8*45*2*2 tiles * 1KB)

    hipLaunchKernelGGL(w_split, dim3(180), dim3(256), 0, stream, w, wp);
    hipLaunchKernelGGL(router_fused, dim3(T_TOK / TM), dim3(NT), 0, stream,
                       x, wp, w, bias, out);
}

// Round 20
// 79.982 us; speedup vs baseline: 1.0258x; 1.0258x over previous
//
#include <hip/hip_runtime.h>
#include <math.h>

// GptOssRouter: T=16384, H=2880, E=128, K=4.
// r20: PRODUCER/CONSUMER WAVE SPECIALIZATION (the documented path past the
// lockstep-phase wall). NT=512, grid=512 (TM=32, 2 blocks/CU).
// Waves 0-3: producers -- load x, split h/l (trunc-exact), ds_write into a
//   4-slot LDS ring, running up to 4 chunks ahead (no block barriers).
// Waves 4-7: consumers -- spin on per-slot LDS counters, ds_read A-frags,
//   24 MFMA/chunk (3-pass split-bf16: xh*wh+xh*wl+xl*wh, err ~1e-5), w frags
//   register-direct from pre-split d_ws (K0, r12 layout).
// Sync: prod_cnt[s] (4 producer waves signal data ready), cons_done[s]
//   (4 consumer waves ack) -- lgkmcnt(0) fences before each signal.
// Epilogue: r12's proven stripe-top8 + certified-gap (TAU=2.5e-4) -> fast
// fp32 softmax; rare fp64 rescore (order == float64 numpy reference).

#define T_TOK 16384
#define HDIM  2880
#define EEXP  128
#define KTOP  4

#define TM   32
#define NT   512
#define KC   64
#define NCH  (HDIM / KC)     // 45
#define XBUF 8192            // 32 rows * 256 B per ring slot
#define TAU  2.5e-4f

typedef __attribute__((ext_vector_type(8))) short bf16x8;
typedef __attribute__((ext_vector_type(4))) float f32x4;

#define MFMA(a, b, c) __builtin_amdgcn_mfma_f32_16x16x32_bf16((a), (b), (c), 0, 0, 0)

// ---------------- K0: w pre-split into fragment-tiled bf16 h/l -------------
__global__ __launch_bounds__(256) void w_split(
    const float* __restrict__ w, char* __restrict__ wp)
{
    const int gid  = blockIdx.x * 256 + threadIdx.x;   // 46080 total
    const int lane = gid & 63;
    const int q    = gid >> 6;        // 0..719
    const int ks   = q & 1;
    const int q2   = q >> 1;          // 0..359
    const int c    = q2 % NCH;
    const int F    = q2 / NCH;        // 0..7
    const int e    = F * 16 + (lane & 15);
    const int k0   = c * 64 + ks * 32 + (lane >> 4) * 8;

    const float* src = w + (size_t)e * HDIM + k0;
    float4 v0 = *(const float4*)(src);
    float4 v1 = *(const float4*)(src + 4);
    float vv[8] = {v0.x, v0.y, v0.z, v0.w, v1.x, v1.y, v1.z, v1.w};
    union { unsigned short s[8]; uint4 u; } H, L;
#pragma unroll
    for (int j = 0; j < 8; ++j) {
        unsigned u = __float_as_uint(vv[j]);
        H.s[j] = (unsigned short)(u >> 16);
        float rr = vv[j] - __uint_as_float(u & 0xffff0000u);
        L.s[j] = (unsigned short)(__float_as_uint(rr) >> 16);
    }
    const int tile = ((F * NCH + c) * 2 + ks) * 2;     // p=0 (h); l at +1
    *(uint4*)(wp + (size_t)tile * 1024 + lane * 16)       = H.u;
    *(uint4*)(wp + (size_t)(tile + 1) * 1024 + lane * 16) = L.u;
}

// x split: v = h + l (h = trunc_bf16(v), l = trunc_bf16(v - h), both exact);
// h 8B at swizzled slot, l at +128 within the 256B row.
static __device__ __forceinline__ void split_write256(char* base, int off, float4 v) {
    union { float4 v4; unsigned u[4]; } uv; uv.v4 = v;
    unsigned h01 = __builtin_amdgcn_perm(uv.u[1], uv.u[0], 0x07060302u);
    unsigned h23 = __builtin_amdgcn_perm(uv.u[3], uv.u[2], 0x07060302u);
    float r0 = v.x - __uint_as_float(uv.u[0] & 0xffff0000u);
    float r1 = v.y - __uint_as_float(uv.u[1] & 0xffff0000u);
    float r2 = v.z - __uint_as_float(uv.u[2] & 0xffff0000u);
    float r3 = v.w - __uint_as_float(uv.u[3] & 0xffff0000u);
    unsigned l01 = __builtin_amdgcn_perm(__float_as_uint(r1), __float_as_uint(r0), 0x07060302u);
    unsigned l23 = __builtin_amdgcn_perm(__float_as_uint(r3), __float_as_uint(r2), 0x07060302u);
    uint2 hw; hw.x = h01; hw.y = h23;
    uint2 lw; lw.x = l01; lw.y = l23;
    *(uint2*)(base + off)       = hw;
    *(uint2*)(base + off + 128) = lw;
}

// ---------------- K1: producer/consumer fused GEMM + selection --------------
__global__ __launch_bounds__(NT, 4) void router_fused(
    const float* __restrict__ x, const char* __restrict__ wp,
    const float* __restrict__ w, const float* __restrict__ bias,
    float* __restrict__ out)
{
    __shared__ char smem[4 * XBUF + 64];   // ring (32KB) + flags
    const int tid  = threadIdx.x;
    const int tok0 = blockIdx.x * TM;
    const int lane = tid & 63;
    const int wv   = tid >> 6;             // 0..7

    volatile unsigned* prod_cnt  = (volatile unsigned*)(smem + 4 * XBUF);        // [4]
    volatile unsigned* cons_done = (volatile unsigned*)(smem + 4 * XBUF + 16);   // [4]
    if (tid < 4) { ((unsigned*)(smem + 4 * XBUF))[tid] = 0u;
                   ((unsigned*)(smem + 4 * XBUF + 16))[tid] = 0u; }
    __syncthreads();

    f32x4 a00 = {0.f, 0.f, 0.f, 0.f}, a01 = a00, a10 = a00, a11 = a00;

    if (wv < 4) {
        // ================= PRODUCERS (waves 0-3) ============================
        int xoff[2];
        const float* xptr[2];
#pragma unroll
        for (int i = 0; i < 2; ++i) {
            int f = tid + i * 256;          // 256 producer threads
            int row = f >> 4, c4 = f & 15;
            xoff[i] = row * 256 + ((((c4 >> 1) ^ (row & 7)) << 4) | ((c4 & 1) << 3));
            xptr[i] = x + (size_t)(tok0 + row) * HDIM + c4 * 4;
        }
        float4 pf0 = *(const float4*)(xptr[0]);
        float4 pf1 = *(const float4*)(xptr[1]);
        for (int c = 0; c < NCH; ++c) {
            const int s = c & 3;
            const unsigned k = (unsigned)(c >> 2);
            while (cons_done[s] < 4u * k) __builtin_amdgcn_s_sleep(2);
            asm volatile("" ::: "memory");
            __builtin_amdgcn_sched_barrier(0);
            char* bb = smem + s * XBUF;
            split_write256(bb, xoff[0], pf0);
            split_write256(bb, xoff[1], pf1);
            if (c + 1 < NCH) {              // prefetch next (in flight over spin)
                pf0 = *(const float4*)(xptr[0] + (c + 1) * KC);
                pf1 = *(const float4*)(xptr[1] + (c + 1) * KC);
            }
            asm volatile("s_waitcnt lgkmcnt(0)" ::: "memory");
            if (lane == 0) atomicAdd((unsigned*)&prod_cnt[s], 1u);
        }
    } else {
        // ================= CONSUMERS (waves 4-7) ============================
        const int cwv = wv - 4;             // expert 32-group
        const int r   = lane & 15;
        const int g   = lane >> 4;
        int aoff[2][2];
#pragma unroll
        for (int tf = 0; tf < 2; ++tf) {
            int row = tf * 16 + r;
#pragma unroll
            for (int ks = 0; ks < 2; ++ks)
                aoff[tf][ks] = row * 256 + (((ks * 4 + g) ^ (row & 7)) << 4);
        }

#define LOADW(W, cc) do {                                             \
        _Pragma("unroll")                                             \
        for (int F2 = 0; F2 < 2; ++F2)                                \
        _Pragma("unroll")                                             \
        for (int ks_ = 0; ks_ < 2; ++ks_)                             \
        _Pragma("unroll")                                             \
        for (int p_ = 0; p_ < 2; ++p_)                                \
            W[F2*4 + ks_*2 + p_] = *(const bf16x8*)(wp +              \
                (size_t)((((cwv*2 + F2) * NCH + (cc)) * 2 + ks_) * 2 + p_) * 1024 \
                + lane * 16); } while (0)

#define MFMA_CHUNK(cb, W) do {                                        \
        _Pragma("unroll")                                             \
        for (int ks_ = 0; ks_ < 2; ++ks_) {                           \
            bf16x8 ah0 = *(const bf16x8*)((cb) + aoff[0][ks_]);       \
            bf16x8 al0 = *(const bf16x8*)((cb) + aoff[0][ks_] + 128); \
            bf16x8 ah1 = *(const bf16x8*)((cb) + aoff[1][ks_]);       \
            bf16x8 al1 = *(const bf16x8*)((cb) + aoff[1][ks_] + 128); \
            bf16x8 bh0 = W[ks_*2],     bl0 = W[ks_*2 + 1];            \
            bf16x8 bh1 = W[4 + ks_*2], bl1 = W[4 + ks_*2 + 1];        \
            a00 = MFMA(ah0, bh0, a00); a01 = MFMA(ah0, bh1, a01);     \
            a10 = MFMA(ah1, bh0, a10); a11 = MFMA(ah1, bh1, a11);     \
            a00 = MFMA(ah0, bl0, a00); a01 = MFMA(ah0, bl1, a01);     \
            a10 = MFMA(ah1, bl0, a10); a11 = MFMA(ah1, bl1, a11);     \
            a00 = MFMA(al0, bh0, a00); a01 = MFMA(al0, bh1, a01);     \
            a10 = MFMA(al1, bh0, a10); a11 = MFMA(al1, bh1, a11);     \
        } } while (0)

#define CONSUME(cc, W) do {                                           \
        const int s_ = (cc) & 3;                                      \
        const unsigned k_ = (unsigned)((cc) >> 2);                    \
        while (prod_cnt[s_] < 4u * (k_ + 1u)) __builtin_amdgcn_s_sleep(2); \
        asm volatile("" ::: "memory");                                \
        __builtin_amdgcn_sched_barrier(0);                            \
        MFMA_CHUNK(smem + s_ * XBUF, W);                              \
        asm volatile("s_waitcnt lgkmcnt(0)" ::: "memory");            \
        __builtin_amdgcn_sched_barrier(0);                            \
        if (lane == 0) atomicAdd((unsigned*)&cons_done[s_], 1u);      \
    } while (0)

        bf16x8 wA[8], wB[8];
        LOADW(wA, 0);
        for (int c = 0; c < 44; c += 2) {
            LOADW(wB, c + 1);
            CONSUME(c, wA);
            LOADW(wA, c + 2);               // c+2 <= 44
            CONSUME(c + 1, wB);
        }
        CONSUME(44, wA);
    }
    __syncthreads();                        // ring dead; safe to overlay

    // -------- logits(+bias) -> LDS [32][130] (consumer waves only) ----------
    float* logitsL = (float*)smem;
    if (wv >= 4) {
        const int cwv = wv - 4;
        const int r   = lane & 15;
        const int g   = lane >> 4;
        const float bv0 = bias[cwv * 32 + r];
        const float bv1 = bias[cwv * 32 + 16 + r];
#pragma unroll
        for (int q = 0; q < 4; ++q) {
            int m0 = g * 4 + q, m1 = m0 + 16;
            int e0 = cwv * 32 + r, e1 = e0 + 16;
            logitsL[m0 * 130 + e0] = a00[q] + bv0;
            logitsL[m0 * 130 + e1] = a01[q] + bv1;
            logitsL[m1 * 130 + e0] = a10[q] + bv0;
            logitsL[m1 * 130 + e1] = a11[q] + bv1;
        }
    }
    float*  cvf = (float*) (smem + 16640);   // [32][8]
    int*    cie = (int*)   (smem + 17664);   // [32][8]
    int*    flg = (int*)   (smem + 18688);   // [32]
    double* svd = (double*)(smem + 18816);   // [32][4]
    int*    sid = (int*)   (smem + 19840);   // [32][4]
    double* cvd = (double*)(smem + 20352);   // [8]
    __syncthreads();

    // -------- stripe top-8: threads 0-255, (t, s) scans 16 experts ----------
    if (tid < 256) {
        const int t = tid >> 3, s = tid & 7;
        float v[8]; int id[8];
#pragma unroll
        for (int k = 0; k < 8; ++k) { v[k] = -3.4e38f; id[k] = 0x7fffffff; }
        for (int jj = 0; jj < 16; ++jj) {
            float lv = logitsL[t * 130 + s * 16 + jj];
            int   e  = s * 16 + jj;
            bool gt[8];
#pragma unroll
            for (int k = 0; k < 8; ++k)
                gt[k] = (lv > v[k]) || (lv == v[k] && e < id[k]);
#pragma unroll
            for (int k = 7; k >= 1; --k)
                if (gt[k - 1]) { v[k] = v[k - 1]; id[k] = id[k - 1]; }
#pragma unroll
            for (int k = 0; k < 8; ++k) {
                bool put = gt[k] && (k == 0 || !gt[k - 1]);
                if (put) { v[k] = lv; id[k] = e; }
            }
        }
#pragma unroll
        for (int rd = 0; rd < 8; ++rd) {
            float hv = v[0]; int hi = id[0];
#pragma unroll
            for (int off = 1; off < 8; off <<= 1) {
                float ov = __shfl_xor(hv, off);
                int   oi = __shfl_xor(hi, off);
                if (ov > hv || (ov == hv && oi < hi)) { hv = ov; hi = oi; }
            }
            if (s == 0) { cvf[t * 8 + rd] = hv; cie[t * 8 + rd] = hi; }
            bool mine = (v[0] == hv) && (id[0] == hi);
            if (mine) {
#pragma unroll
                for (int k = 0; k < 7; ++k) { v[k] = v[k + 1]; id[k] = id[k + 1]; }
                v[7] = -3.4e38f; id[7] = 0x7fffffff;
            }
        }
    }
    __syncthreads();

    // -------- certified-gap test + fast-path fill ---------------------------
    if (tid < TM) {
        float gmin = 3.4e38f;
#pragma unroll
        for (int k = 0; k < 4; ++k)
            gmin = fminf(gmin, cvf[tid * 8 + k] - cvf[tid * 8 + k + 1]);
        flg[tid] = (gmin < TAU);
    }
    if (tid < 128) {
        int t2 = tid >> 2, k = tid & 3;
        svd[t2 * 4 + k] = (double)cvf[t2 * 8 + k];
        sid[t2 * 4 + k] = cie[t2 * 8 + k];
    }
    __syncthreads();

    // -------- rare slow path: fp64 rescore (1 candidate per wave) -----------
    for (int ts = 0; ts < TM; ++ts) {
        if (!flg[ts]) continue;              // uniform across block
        {
            const int ce = cie[ts * 8 + wv];
            const float4* xr = (const float4*)(x + (size_t)(tok0 + ts) * HDIM);
            const float4* wr = (const float4*)(w + (size_t)ce * HDIM);
            double q0 = 0.0, q1 = 0.0, q2 = 0.0, q3 = 0.0;
            for (int i2 = 0; i2 < 12; ++i2) {
                int fi = lane + i2 * 64;
                if (fi < HDIM / 4) {
                    float4 xv = xr[fi];
                    float4 wv4 = wr[fi];
                    q0 = fma((double)xv.x, (double)wv4.x, q0);
                    q1 = fma((double)xv.y, (double)wv4.y, q1);
                    q2 = fma((double)xv.z, (double)wv4.z, q2);
                    q3 = fma((double)xv.w, (double)wv4.w, q3);
                }
            }
            double accd = (q0 + q2) + (q1 + q3);
#pragma unroll
            for (int off = 32; off > 0; off >>= 1)
                accd += __shfl_xor(accd, off);
            if (lane == 0) cvd[wv] = accd + (double)bias[ce];
        }
        __syncthreads();
        if (tid < 8) {                        // fp64 rank among 8 candidates
            double mv = cvd[tid]; int mi2 = cie[ts * 8 + tid];
            int rk = 0;
#pragma unroll
            for (int j2 = 0; j2 < 8; ++j2) {
                double oj = cvd[j2];
                rk += (oj > mv) || (oj == mv && cie[ts * 8 + j2] < mi2);
            }
            if (rk < 4) { svd[ts * 4 + rk] = mv; sid[ts * 4 + rk] = mi2; }
        }
        __syncthreads();
    }

    // -------- softmax + outputs ---------------------------------------------
    float* srow = (float*)smem;              // [32][128], overlays dead logits
    float4 z4 = make_float4(0.f, 0.f, 0.f, 0.f);
#pragma unroll
    for (int i = 0; i < 2; ++i)
        ((float4*)srow)[tid + i * NT] = z4;
    __syncthreads();

    if (tid < TM) {
        double m  = svd[tid * 4];
        double e0 = exp(svd[tid * 4 + 0] - m), e1 = exp(svd[tid * 4 + 1] - m);
        double e2 = exp(svd[tid * 4 + 2] - m), e3 = exp(svd[tid * 4 + 3] - m);
        double inv = 1.0 / ((e0 + e1) + (e2 + e3));
        float* oidx = out + (size_t)T_TOK * EEXP + (size_t)(tok0 + tid) * KTOP;
        int i0 = sid[tid * 4 + 0], i1 = sid[tid * 4 + 1];
        int i2 = sid[tid * 4 + 2], i3 = sid[tid * 4 + 3];
        oidx[0] = (float)i0; oidx[1] = (float)i1;
        oidx[2] = (float)i2; oidx[3] = (float)i3;
        srow[tid * EEXP + i0] = (float)(e0 * inv);
        srow[tid * EEXP + i1] = (float)(e1 * inv);
        srow[tid * EEXP + i2] = (float)(e2 * inv);
        srow[tid * EEXP + i3] = (float)(e3 * inv);
    }
    __syncthreads();

    float4* orow = (float4*)(out + (size_t)tok0 * EEXP);
#pragma unroll
    for (int i = 0; i < 2; ++i)
        orow[tid + i * NT] = ((float4*)srow)[tid + i * NT];
}

extern "C" void kernel_launch(void* const* d_in, const int* in_sizes, int n_in,
                              void* d_out, int out_size, void* d_ws, size_t ws_size,
                              hipStream_t stream) {
    const float* x    = (const float*)d_in[0];
    const float* w    = (const float*)d_in[1];
    const float* bias = (const float*)d_in[2];
    float* out        = (float*)d_out;
    char*  wp         = (char*)d_ws;   // 1440 KiB (8*45*2*2 tiles * 1KB)

    hipLaunchKernelGGL(w_split, dim3(180), dim3(256), 0, stream, w, wp);
    hipLaunchKernelGGL(router_fused, dim3(T_TOK / TM), dim3(NT), 0, stream,
                       x, wp, w, bias, out);
}

// Round 21
// 79.091 us; speedup vs baseline: 1.0373x; 1.0113x over previous
//
#include <hip/hip_runtime.h>
#include <math.h>

// GptOssRouter: T=16384, H=2880, E=128, K=4.
// r21: SINGLE-PASS FP16 (cuts bytes+VALU+MFMA 2-3x vs 3-pass split-bf16).
// fp16 RNE logit err sigma ~4.3e-4 -> certified-gap TAU=4e-3 (~6.6 sigma of
// diff-err): fast path = fp32 softmax of fp16-GEMM logits; ~5% of tokens
// flagged -> fp64 rescore of their top-8 (order == float64 numpy reference).
// K0: w pre-convert fp32->fp16 (RNE) into d_ws as 16x16x32 B-frag tiles.
// K1: r12 skeleton (best: 80.2us): 32 tok x 128 exp per block, grid=512,
//     depth-3 reg/LDS pipeline, swizzled fp16 x-LDS (128B rows), w frags
//     register-direct from d_ws.

#define T_TOK 16384
#define HDIM  2880
#define EEXP  128
#define KTOP  4

#define TM   32
#define NT   256
#define KC   64              // halfs per chunk per row
#define NCH  (HDIM / KC)     // 45 = 15 * 3
#define XBUF 4096            // 32 rows * 128 B fp16
#define TAU  4e-3f

typedef __attribute__((ext_vector_type(8))) _Float16 f16x8;
typedef __attribute__((ext_vector_type(4))) float    f32x4;

#define MFMA(a, b, c) __builtin_amdgcn_mfma_f32_16x16x32_f16((a), (b), (c), 0, 0, 0)

// ---------------- K0: w pre-convert into fragment-tiled fp16 ----------------
__global__ __launch_bounds__(256) void w_cvt(
    const float* __restrict__ w, char* __restrict__ wp)
{
    const int gid  = blockIdx.x * 256 + threadIdx.x;   // 46080 = 720 tiles * 64
    const int lane = gid & 63;
    const int q    = gid >> 6;        // 0..719
    const int ks   = q & 1;
    const int q2   = q >> 1;          // 0..359
    const int c    = q2 % NCH;
    const int F    = q2 / NCH;        // 0..7
    const int e    = F * 16 + (lane & 15);
    const int k0   = c * 64 + ks * 32 + (lane >> 4) * 8;

    const float* src = w + (size_t)e * HDIM + k0;
    float4 v0 = *(const float4*)(src);
    float4 v1 = *(const float4*)(src + 4);
    union { _Float16 h[8]; uint4 u; } H;
    H.h[0] = (_Float16)v0.x; H.h[1] = (_Float16)v0.y;
    H.h[2] = (_Float16)v0.z; H.h[3] = (_Float16)v0.w;
    H.h[4] = (_Float16)v1.x; H.h[5] = (_Float16)v1.y;
    H.h[6] = (_Float16)v1.z; H.h[7] = (_Float16)v1.w;
    const int tile = (F * NCH + c) * 2 + ks;
    *(uint4*)(wp + (size_t)tile * 1024 + lane * 16) = H.u;
}

// x staging: float4 -> 4 fp16 (RNE), 8B at swizzled slot within 128B row.
static __device__ __forceinline__ void cvt_write128(char* base, int off, float4 v) {
    union { _Float16 h[4]; uint2 u; } U;
    U.h[0] = (_Float16)v.x; U.h[1] = (_Float16)v.y;
    U.h[2] = (_Float16)v.z; U.h[3] = (_Float16)v.w;
    *(uint2*)(base + off) = U.u;
}

// ---------------- K1: fused GEMM + selection --------------------------------
__global__ __launch_bounds__(NT, 2) void router_fused(
    const float* __restrict__ x, const char* __restrict__ wp,
    const float* __restrict__ w, const float* __restrict__ bias,
    float* __restrict__ out)
{
    __shared__ char smem[20480];        // 3 x-bufs (12KB) / epilogue overlay
    const int tid  = threadIdx.x;
    const int tok0 = blockIdx.x * TM;
    const int lane = tid & 63;
    const int wv   = tid >> 6;          // expert 32-group 0..3
    const int r    = lane & 15;
    const int g    = lane >> 4;

    char* xb0 = smem;
    char* xb1 = smem + XBUF;
    char* xb2 = smem + 2 * XBUF;

    // x staging map: 512 float4 / 256 thr = 2 per thread
    int xoff[2];
    const float* xptr[2];
#pragma unroll
    for (int i = 0; i < 2; ++i) {
        int f = tid + i * NT;
        int row = f >> 4, c4 = f & 15;
        xoff[i] = row * 128 + ((((c4 >> 1) ^ (row & 7)) << 4) | ((c4 & 1) << 3));
        xptr[i] = x + (size_t)(tok0 + row) * HDIM + c4 * 4;
    }

    // a-frag read offsets: [tokfrag][ks]; logical slot = ks*4+g, XOR row&7
    int aoff[2][2];
#pragma unroll
    for (int tf = 0; tf < 2; ++tf) {
        int row = tf * 16 + r;
#pragma unroll
        for (int ks = 0; ks < 2; ++ks)
            aoff[tf][ks] = row * 128 + (((ks * 4 + g) ^ (row & 7)) << 4);
    }

    f32x4 a00 = {0.f, 0.f, 0.f, 0.f}, a01 = a00, a10 = a00, a11 = a00;

#define LOADX(pf, cc) do {                                            \
        pf[0] = *(const float4*)(xptr[0] + (cc) * KC);                \
        pf[1] = *(const float4*)(xptr[1] + (cc) * KC); } while (0)

#define WRITEX(pf, bb) do {                                           \
        cvt_write128((bb), xoff[0], pf[0]);                           \
        cvt_write128((bb), xoff[1], pf[1]); } while (0)

    // w frag tiles: W[F2*2 + ks]
#define LOADW(W, cc) do {                                             \
        _Pragma("unroll")                                             \
        for (int F2 = 0; F2 < 2; ++F2)                                \
        _Pragma("unroll")                                             \
        for (int ks_ = 0; ks_ < 2; ++ks_)                             \
            W[F2*2 + ks_] = *(const f16x8*)(wp +                      \
                (size_t)(((wv*2 + F2) * NCH + (cc)) * 2 + ks_) * 1024 \
                + lane * 16); } while (0)

#define MFMA_CHUNK(cb, W) do {                                        \
        _Pragma("unroll")                                             \
        for (int ks_ = 0; ks_ < 2; ++ks_) {                           \
            f16x8 a0 = *(const f16x8*)((cb) + aoff[0][ks_]);          \
            f16x8 a1 = *(const f16x8*)((cb) + aoff[1][ks_]);          \
            a00 = MFMA(a0, W[ks_],     a00);                          \
            a01 = MFMA(a0, W[2 + ks_], a01);                          \
            a10 = MFMA(a1, W[ks_],     a10);                          \
            a11 = MFMA(a1, W[2 + ks_], a11);                          \
        } } while (0)

    float4 pfA[2], pfB[2], pfC[2];
    f16x8 wA[4], wB[4], wC[4];

    // prologue: chunks 0..2 in regs, chunk 0 -> xb0; w chunks 0,1 in regs
    LOADX(pfA, 0); LOADX(pfB, 1); LOADX(pfC, 2);
    LOADW(wA, 0); LOADW(wB, 1);
    WRITEX(pfA, xb0);
    __syncthreads();

    for (int c = 0; c < NCH; c += 3) {
        // ---- phase 0: chunk c on xb0 / wA --------------------------------
        if (c + 3 < NCH) LOADX(pfA, c + 3);
        LOADW(wC, c + 2);
        MFMA_CHUNK(xb0, wA);
        WRITEX(pfB, xb1);                 // chunk c+1 (loaded 3 phases ago)
        __syncthreads();
        // ---- phase 1: chunk c+1 on xb1 / wB ------------------------------
        if (c + 3 < NCH) LOADW(wA, c + 3);
        if (c + 4 < NCH) LOADX(pfB, c + 4);
        MFMA_CHUNK(xb1, wB);
        WRITEX(pfC, xb2);                 // chunk c+2
        __syncthreads();
        // ---- phase 2: chunk c+2 on xb2 / wC ------------------------------
        if (c + 4 < NCH) LOADW(wB, c + 4);
        if (c + 5 < NCH) LOADX(pfC, c + 5);
        MFMA_CHUNK(xb2, wC);
        if (c + 3 < NCH) WRITEX(pfA, xb0); // chunk c+3
        __syncthreads();
    }

    // -------- logits(+bias) -> LDS [32][130] --------------------------------
    float* logitsL = (float*)smem;
    const float bv0 = bias[wv * 32 + r];
    const float bv1 = bias[wv * 32 + 16 + r];
#pragma unroll
    for (int q = 0; q < 4; ++q) {
        int m0 = g * 4 + q, m1 = m0 + 16;
        int e0 = wv * 32 + r, e1 = e0 + 16;
        logitsL[m0 * 130 + e0] = a00[q] + bv0;
        logitsL[m0 * 130 + e1] = a01[q] + bv1;
        logitsL[m1 * 130 + e0] = a10[q] + bv0;
        logitsL[m1 * 130 + e1] = a11[q] + bv1;
    }
    float*  cvf = (float*) (smem + 16640);   // [32][8]
    int*    cie = (int*)   (smem + 17664);   // [32][8]
    int*    flg = (int*)   (smem + 18688);   // [32]
    double* svd = (double*)(smem + 18816);   // [32][4]
    int*    sid = (int*)   (smem + 19840);   // [32][4]
    double* cvd = (double*)(smem + 20352);   // [8]
    __syncthreads();

    // -------- stripe top-8: thread (t, s) scans experts [s*16, s*16+16) -----
    {
        const int t = tid >> 3, s = tid & 7;
        float v[8]; int id[8];
#pragma unroll
        for (int k = 0; k < 8; ++k) { v[k] = -3.4e38f; id[k] = 0x7fffffff; }
        for (int jj = 0; jj < 16; ++jj) {
            float lv = logitsL[t * 130 + s * 16 + jj];
            int   e  = s * 16 + jj;
            bool gt[8];
#pragma unroll
            for (int k = 0; k < 8; ++k)
                gt[k] = (lv > v[k]) || (lv == v[k] && e < id[k]);
#pragma unroll
            for (int k = 7; k >= 1; --k)
                if (gt[k - 1]) { v[k] = v[k - 1]; id[k] = id[k - 1]; }
#pragma unroll
            for (int k = 0; k < 8; ++k) {
                bool put = gt[k] && (k == 0 || !gt[k - 1]);
                if (put) { v[k] = lv; id[k] = e; }
            }
        }
#pragma unroll
        for (int rd = 0; rd < 8; ++rd) {
            float hv = v[0]; int hi = id[0];
#pragma unroll
            for (int off = 1; off < 8; off <<= 1) {
                float ov = __shfl_xor(hv, off);
                int   oi = __shfl_xor(hi, off);
                if (ov > hv || (ov == hv && oi < hi)) { hv = ov; hi = oi; }
            }
            if (s == 0) { cvf[t * 8 + rd] = hv; cie[t * 8 + rd] = hi; }
            bool mine = (v[0] == hv) && (id[0] == hi);
            if (mine) {
#pragma unroll
                for (int k = 0; k < 7; ++k) { v[k] = v[k + 1]; id[k] = id[k + 1]; }
                v[7] = -3.4e38f; id[7] = 0x7fffffff;
            }
        }
    }
    __syncthreads();

    // -------- certified-gap test + fast-path fill ---------------------------
    if (tid < TM) {
        float gmin = 3.4e38f;
#pragma unroll
        for (int k = 0; k < 4; ++k)
            gmin = fminf(gmin, cvf[tid * 8 + k] - cvf[tid * 8 + k + 1]);
        flg[tid] = (gmin < TAU);
    }
    if (tid < 128) {
        int t2 = tid >> 2, k = tid & 3;
        svd[t2 * 4 + k] = (double)cvf[t2 * 8 + k];
        sid[t2 * 4 + k] = cie[t2 * 8 + k];
    }
    __syncthreads();

    // -------- slow path (~5% tokens): fp64 rescore, 2 candidates per wave ---
    for (int ts = 0; ts < TM; ++ts) {
        if (!flg[ts]) continue;              // uniform across block
#pragma unroll
        for (int h2 = 0; h2 < 2; ++h2) {
            const int cand = wv * 2 + h2;
            const int ce = cie[ts * 8 + cand];
            const float4* xr = (const float4*)(x + (size_t)(tok0 + ts) * HDIM);
            const float4* wr = (const float4*)(w + (size_t)ce * HDIM);
            double q0 = 0.0, q1 = 0.0, q2 = 0.0, q3 = 0.0;
            for (int i2 = 0; i2 < 12; ++i2) {
                int fi = lane + i2 * 64;
                if (fi < HDIM / 4) {
                    float4 xv = xr[fi];
                    float4 wv4 = wr[fi];
                    q0 = fma((double)xv.x, (double)wv4.x, q0);
                    q1 = fma((double)xv.y, (double)wv4.y, q1);
                    q2 = fma((double)xv.z, (double)wv4.z, q2);
                    q3 = fma((double)xv.w, (double)wv4.w, q3);
                }
            }
            double accd = (q0 + q2) + (q1 + q3);
#pragma unroll
            for (int off = 32; off > 0; off >>= 1)
                accd += __shfl_xor(accd, off);
            if (lane == 0) cvd[cand] = accd + (double)bias[ce];
        }
        __syncthreads();
        if (tid < 8) {                        // fp64 rank among 8 candidates
            double mv = cvd[tid]; int mi2 = cie[ts * 8 + tid];
            int rk = 0;
#pragma unroll
            for (int j2 = 0; j2 < 8; ++j2) {
                double oj = cvd[j2];
                rk += (oj > mv) || (oj == mv && cie[ts * 8 + j2] < mi2);
            }
            if (rk < 4) { svd[ts * 4 + rk] = mv; sid[ts * 4 + rk] = mi2; }
        }
        __syncthreads();
    }

    // -------- softmax + outputs ---------------------------------------------
    float* srow = (float*)smem;              // [32][128], overlays dead logits
    float4 z4 = make_float4(0.f, 0.f, 0.f, 0.f);
#pragma unroll
    for (int i = 0; i < 4; ++i)
        ((float4*)srow)[tid + i * NT] = z4;
    __syncthreads();

    if (tid < TM) {
        double m  = svd[tid * 4];
        double e0 = exp(svd[tid * 4 + 0] - m), e1 = exp(svd[tid * 4 + 1] - m);
        double e2 = exp(svd[tid * 4 + 2] - m), e3 = exp(svd[tid * 4 + 3] - m);
        double inv = 1.0 / ((e0 + e1) + (e2 + e3));
        float* oidx = out + (size_t)T_TOK * EEXP + (size_t)(tok0 + tid) * KTOP;
        int i0 = sid[tid * 4 + 0], i1 = sid[tid * 4 + 1];
        int i2 = sid[tid * 4 + 2], i3 = sid[tid * 4 + 3];
        oidx[0] = (float)i0; oidx[1] = (float)i1;
        oidx[2] = (float)i2; oidx[3] = (float)i3;
        srow[tid * EEXP + i0] = (float)(e0 * inv);
        srow[tid * EEXP + i1] = (float)(e1 * inv);
        srow[tid * EEXP + i2] = (float)(e2 * inv);
        srow[tid * EEXP + i3] = (float)(e3 * inv);
    }
    __syncthreads();

    float4* orow = (float4*)(out + (size_t)tok0 * EEXP);
#pragma unroll
    for (int i = 0; i < 4; ++i)
        orow[tid + i * NT] = ((float4*)srow)[tid + i * NT];
}

extern "C" void kernel_launch(void* const* d_in, const int* in_sizes, int n_in,
                              void* d_out, int out_size, void* d_ws, size_t ws_size,
                              hipStream_t stream) {
    const float* x    = (const float*)d_in[0];
    const float* w    = (const float*)d_in[1];
    const float* bias = (const float*)d_in[2];
    float* out        = (float*)d_out;
    char*  wp         = (char*)d_ws;   // 720 KiB (8*45*2 tiles * 1KB)

    hipLaunchKernelGGL(w_cvt, dim3(180), dim3(256), 0, stream, w, wp);
    hipLaunchKernelGGL(router_fused, dim3(T_TOK / TM), dim3(NT), 0, stream,
                       x, wp, w, bias, out);
}